// Round 1
// 165.054 us; speedup vs baseline: 1.0254x; 1.0254x over previous
//
#include <hip/hip_runtime.h>

// CoordinateLoss: masked Kabsch (Horn quaternion) + Huber loss.
// B=256, S=16384, fp32 coords, int32 mask.
//
// R10: FUSED single-pass design. One block == one batch (512 thr x 32 pts).
// All 16384 points of a batch live in registers (masked mP,mT = 192 VGPR,
// mask as 1 bitmask reg). Covariance -> block reduce -> thread-0 Horn solve
// -> in-register Huber. Eliminates the entire second 117 MB global pass
// (old loss_kernel, ~35us) and the svd_kernel launch. Journal history:
// R6 no single-address atomics; R5 power-iter on N/fro; R8 transaction
// pattern not the limiter; R9 first pass pinned ~41us (~2.9 TB/s wall).

#define NB 256       // batches == blocks
#define NS 16384     // points per batch
#define TPB 512      // threads per block (8 waves)
#define PPT 32       // points per thread; TPB*PPT == NS
#define NW (TPB / 64)

__device__ __forceinline__ float wave_sum(float v) {
#pragma unroll
    for (int o = 32; o > 0; o >>= 1) v += __shfl_xor(v, o, 64);
    return v;
}

__device__ __forceinline__ float huber(float d) {
    float a = fabsf(d);
    return a < 1.f ? 0.5f * d * d : a - 0.5f;
}

// One block per batch. __launch_bounds__(512, 2): 2 waves/EU -> 1 block/CU,
// VGPR cap 256 (data = 192 + acc 16 + temps fits without spill).
__global__ __launch_bounds__(TPB, 2) void fused_kernel(
    const float* __restrict__ pred, const float* __restrict__ tgt,
    const int* __restrict__ mask,
    float* __restrict__ bl, float* __restrict__ bc)
{
    const int b = blockIdx.x, tid = threadIdx.x;
    const long base = (long)b * NS + (long)tid * PPT;
    const float4* p4 = reinterpret_cast<const float4*>(pred + base * 3);
    const float4* t4 = reinterpret_cast<const float4*>(tgt + base * 3);
    const int4*   m4 = reinterpret_cast<const int4*>(mask + base);

    // Persistent masked coordinates (m in {0,1}; m^2 == m so masked values
    // serve both the covariance sums and the loss pass).
    float Px[PPT], Py[PPT], Pz[PPT], Tx[PPT], Ty[PPT], Tz[PPT];
    unsigned int mbits = 0u;

    float acc[16];
#pragma unroll
    for (int i = 0; i < 16; ++i) acc[i] = 0.f;

#pragma unroll
    for (int g = 0; g < PPT / 4; ++g) {
        const float4 pA = p4[3*g], pB = p4[3*g+1], pC = p4[3*g+2];
        const float4 tA = t4[3*g], tB = t4[3*g+1], tC = t4[3*g+2];
        const int4 mm = m4[g];
        const float P[4][3] = {{pA.x,pA.y,pA.z},{pA.w,pB.x,pB.y},
                               {pB.z,pB.w,pC.x},{pC.y,pC.z,pC.w}};
        const float T[4][3] = {{tA.x,tA.y,tA.z},{tA.w,tB.x,tB.y},
                               {tB.z,tB.w,tC.x},{tC.y,tC.z,tC.w}};
        const int mi[4] = {mm.x, mm.y, mm.z, mm.w};
#pragma unroll
        for (int k = 0; k < 4; ++k) {
            const int idx = g * 4 + k;
            const float mk = mi[k] ? 1.f : 0.f;
            mbits |= (mi[k] ? 1u : 0u) << idx;
            const float px = mk * P[k][0], py = mk * P[k][1], pz = mk * P[k][2];
            const float tx = mk * T[k][0], ty = mk * T[k][1], tz = mk * T[k][2];
            Px[idx] = px; Py[idx] = py; Pz[idx] = pz;
            Tx[idx] = tx; Ty[idx] = ty; Tz[idx] = tz;
            acc[0] += mk;
            acc[1] += px;  acc[2] += py;  acc[3] += pz;
            acc[4] += tx;  acc[5] += ty;  acc[6] += tz;
            acc[7]  += px * tx; acc[8]  += px * ty; acc[9]  += px * tz;
            acc[10] += py * tx; acc[11] += py * ty; acc[12] += py * tz;
            acc[13] += pz * tx; acc[14] += pz * ty; acc[15] += pz * tz;
        }
    }

#pragma unroll
    for (int i = 0; i < 16; ++i) acc[i] = wave_sum(acc[i]);

    __shared__ float red[NW][16];
    __shared__ float Ssum[16];
    __shared__ float C[13];
    const int wave = tid >> 6, lane = tid & 63;
    if (lane == 0) {
#pragma unroll
        for (int i = 0; i < 16; ++i) red[wave][i] = acc[i];
    }
    __syncthreads();
    if (tid < 16) {
        float s = 0.f;
#pragma unroll
        for (int w = 0; w < NW; ++w) s += red[w][tid];
        Ssum[tid] = s;
    }
    __syncthreads();

    if (tid == 0) {
        const float cnt = Ssum[0];
        const float inv = 1.f / cnt;
        const float cpx = Ssum[1]*inv, cpy = Ssum[2]*inv, cpz = Ssum[3]*inv;
        const float ctx = Ssum[4]*inv, cty = Ssum[5]*inv, ctz = Ssum[6]*inv;
        const float Sxx = Ssum[7]  - cnt*cpx*ctx;
        const float Sxy = Ssum[8]  - cnt*cpx*cty;
        const float Sxz = Ssum[9]  - cnt*cpx*ctz;
        const float Syx = Ssum[10] - cnt*cpy*ctx;
        const float Syy = Ssum[11] - cnt*cpy*cty;
        const float Syz = Ssum[12] - cnt*cpy*ctz;
        const float Szx = Ssum[13] - cnt*cpz*ctx;
        const float Szy = Ssum[14] - cnt*cpz*cty;
        const float Szz = Ssum[15] - cnt*cpz*ctz;
        // Horn's 4x4 N: max-eigvec quaternion == Kabsch R with det(+1) fix.
        float N00 =  Sxx + Syy + Szz;
        float N01 =  Syz - Szy;
        float N02 =  Szx - Sxz;
        float N03 =  Sxy - Syx;
        float N11 =  Sxx - Syy - Szz;
        float N12 =  Sxy + Syx;
        float N13 =  Szx + Sxz;
        float N22 = -Sxx + Syy - Szz;
        float N23 =  Syz + Szy;
        float N33 = -Sxx - Syy + Szz;
        const float fro = sqrtf(N00*N00 + N11*N11 + N22*N22 + N33*N33 +
              2.f*(N01*N01 + N02*N02 + N03*N03 + N12*N12 + N13*N13 + N23*N23));
        // Spectral radius of (N/fro + I) <= 2; norm every 8 iters (R5 fix).
        const float isc = 1.f / (fro + 1e-30f);
        N00*=isc; N01*=isc; N02*=isc; N03*=isc; N11*=isc;
        N12*=isc; N13*=isc; N22*=isc; N23*=isc; N33*=isc;

        float qw = 1.f, qx = 0.1f, qy = 0.2f, qz = 0.3f;
        for (int it = 0; it < 96; ++it) {
            float nw = N00*qw + N01*qx + N02*qy + N03*qz + qw;
            float nx = N01*qw + N11*qx + N12*qy + N13*qz + qx;
            float ny = N02*qw + N12*qx + N22*qy + N23*qz + qy;
            float nz = N03*qw + N13*qx + N23*qy + N33*qz + qz;
            if ((it & 7) == 7) {
                const float r = rsqrtf(nw*nw + nx*nx + ny*ny + nz*nz);
                nw *= r; nx *= r; ny *= r; nz *= r;
            }
            qw = nw; qx = nx; qy = ny; qz = nz;
        }
        const float r = rsqrtf(qw*qw + qx*qx + qy*qy + qz*qz);
        qw *= r; qx *= r; qy *= r; qz *= r;
        const float R00 = 1.f - 2.f*(qy*qy + qz*qz);
        const float R01 = 2.f*(qx*qy - qw*qz);
        const float R02 = 2.f*(qx*qz + qw*qy);
        const float R10 = 2.f*(qx*qy + qw*qz);
        const float R11 = 1.f - 2.f*(qx*qx + qz*qz);
        const float R12 = 2.f*(qy*qz - qw*qx);
        const float R20 = 2.f*(qx*qz - qw*qy);
        const float R21 = 2.f*(qy*qz + qw*qx);
        const float R22 = 1.f - 2.f*(qx*qx + qy*qy);
        C[0]=R00; C[1]=R01; C[2]=R02;
        C[3]=R10; C[4]=R11; C[5]=R12;
        C[6]=R20; C[7]=R21; C[8]=R22;
        C[9]  = ctx - (R00*cpx + R01*cpy + R02*cpz);
        C[10] = cty - (R10*cpx + R11*cpy + R12*cpz);
        C[11] = ctz - (R20*cpx + R21*cpy + R22*cpz);
        C[12] = cnt;
    }
    __syncthreads();

    // ---- loss from register-resident points (no global re-read) ----
    const float C0=C[0], C1=C[1], C2=C[2], C3=C[3], C4=C[4],  C5=C[5];
    const float C6=C[6], C7=C[7], C8=C[8], C9=C[9], C10=C[10], C11=C[11];
    float ls = 0.f;
#pragma unroll
    for (int k = 0; k < PPT; ++k) {
        const float mk = (float)((mbits >> k) & 1u);
        const float ax = C0*Px[k] + C1*Py[k] + C2*Pz[k] + C9;
        const float ay = C3*Px[k] + C4*Py[k] + C5*Pz[k] + C10;
        const float az = C6*Px[k] + C7*Py[k] + C8*Pz[k] + C11;
        ls += mk * (huber(ax - Tx[k]) + huber(ay - Ty[k]) + huber(az - Tz[k]));
    }
    ls = wave_sum(ls);
    __shared__ float redl[NW];
    if (lane == 0) redl[wave] = ls;
    __syncthreads();
    if (tid == 0) {
        float t = 0.f;
#pragma unroll
        for (int w = 0; w < NW; ++w) t += redl[w];
        bl[b] = t;
        bc[b] = C[12];
    }
}

// ---- final scalar = sum(bl) / sum(bc) over 256 batches ----
__global__ __launch_bounds__(NB) void final_kernel(
    const float* __restrict__ bl, const float* __restrict__ bc,
    float* __restrict__ out)
{
    const int tid = threadIdx.x;
    float ls = bl[tid];
    float cs = bc[tid];
    ls = wave_sum(ls);
    cs = wave_sum(cs);
    __shared__ float rl[4], rc[4];
    const int wave = tid >> 6, lane = tid & 63;
    if (lane == 0) { rl[wave] = ls; rc[wave] = cs; }
    __syncthreads();
    if (tid == 0)
        out[0] = (rl[0]+rl[1]+rl[2]+rl[3]) / (rc[0]+rc[1]+rc[2]+rc[3]);
}

extern "C" void kernel_launch(void* const* d_in, const int* in_sizes, int n_in,
                              void* d_out, int out_size, void* d_ws, size_t ws_size,
                              hipStream_t stream) {
    const float* pred = (const float*)d_in[0];
    const float* tgt  = (const float*)d_in[1];
    const int*   mask = (const int*)d_in[2];
    float* out = (float*)d_out;

    // ws layout (floats): bl[256] | bc[256]
    float* bl = (float*)d_ws;
    float* bc = bl + NB;

    fused_kernel<<<NB, TPB, 0, stream>>>(pred, tgt, mask, bl, bc);
    final_kernel<<<1, NB, 0, stream>>>(bl, bc, out);
}

// Round 2
// 157.001 us; speedup vs baseline: 1.0780x; 1.0513x over previous
//
#include <hip/hip_runtime.h>

// CoordinateLoss: masked Kabsch (Horn quaternion) + Huber loss.
// B=256, S=16384, fp32 coords, int32 mask.
//
// R11: fused one-block-per-batch, REDUCED register payload. R10 post-mortem:
// storing mP+mT (192 floats) spilled -- compiler chose 128 VGPR despite
// launch_bounds(512,2) and wrote 21.6 MB scratch (WRITE_SIZE evidence).
// Fix: keep only masked P (96 VGPR) + mask bitmask; re-read tgt in the loss
// phase (L3-warm: 117 MB total working set < 256 MB Infinity Cache). Pin
// allocator with amdgpu_waves_per_eu(2,2) so it uses the full 256-VGPR
// budget instead of targeting higher occupancy and spilling.
// History: R9 phase-1 streaming pinned ~41us (~2.9 TB/s first-touch wall);
// R8 transaction pattern not the limiter; R6 no single-address atomics;
// R5 power-iter on N/fro only.

#define NB 256       // batches == blocks
#define NS 16384     // points per batch
#define TPB 512      // threads per block (8 waves)
#define PPT 32       // points per thread; TPB*PPT == NS
#define NW (TPB / 64)

__device__ __forceinline__ float wave_sum(float v) {
#pragma unroll
    for (int o = 32; o > 0; o >>= 1) v += __shfl_xor(v, o, 64);
    return v;
}

__device__ __forceinline__ float huber(float d) {
    float a = fabsf(d);
    return a < 1.f ? 0.5f * d * d : a - 0.5f;
}

// One block per batch; 1 block/CU. waves_per_eu(2,2) pins occupancy so the
// register allocator uses the full 256-VGPR/wave budget (R10: it chose 128
// and spilled 21.6 MB to scratch).
__global__ __launch_bounds__(TPB)
__attribute__((amdgpu_waves_per_eu(2, 2)))
void fused_kernel(
    const float* __restrict__ pred, const float* __restrict__ tgt,
    const int* __restrict__ mask,
    float* __restrict__ bl, float* __restrict__ bc)
{
    const int b = blockIdx.x, tid = threadIdx.x;
    const long base = (long)b * NS + (long)tid * PPT;
    const float4* p4 = reinterpret_cast<const float4*>(pred + base * 3);
    const float4* t4 = reinterpret_cast<const float4*>(tgt + base * 3);
    const int4*   m4 = reinterpret_cast<const int4*>(mask + base);

    // Persistent: masked pred only (96 VGPR) + 32-bit mask. m in {0,1} and
    // m^2 == m, so masked P serves covariance AND loss; tgt is re-read
    // (L3-warm) in the loss phase instead of being register-resident.
    float Px[PPT], Py[PPT], Pz[PPT];
    unsigned int mbits = 0u;

    float acc[16];
#pragma unroll
    for (int i = 0; i < 16; ++i) acc[i] = 0.f;

#pragma unroll
    for (int g = 0; g < PPT / 4; ++g) {
        const float4 pA = p4[3*g], pB = p4[3*g+1], pC = p4[3*g+2];
        const float4 tA = t4[3*g], tB = t4[3*g+1], tC = t4[3*g+2];
        const int4 mm = m4[g];
        const float P[4][3] = {{pA.x,pA.y,pA.z},{pA.w,pB.x,pB.y},
                               {pB.z,pB.w,pC.x},{pC.y,pC.z,pC.w}};
        const float T[4][3] = {{tA.x,tA.y,tA.z},{tA.w,tB.x,tB.y},
                               {tB.z,tB.w,tC.x},{tC.y,tC.z,tC.w}};
        const int mi[4] = {mm.x, mm.y, mm.z, mm.w};
#pragma unroll
        for (int k = 0; k < 4; ++k) {
            const int idx = g * 4 + k;
            const float mk = mi[k] ? 1.f : 0.f;
            mbits |= (mi[k] ? 1u : 0u) << idx;
            const float px = mk * P[k][0], py = mk * P[k][1], pz = mk * P[k][2];
            const float tx = mk * T[k][0], ty = mk * T[k][1], tz = mk * T[k][2];
            Px[idx] = px; Py[idx] = py; Pz[idx] = pz;
            acc[0] += mk;
            acc[1] += px;  acc[2] += py;  acc[3] += pz;
            acc[4] += tx;  acc[5] += ty;  acc[6] += tz;
            acc[7]  += px * tx; acc[8]  += px * ty; acc[9]  += px * tz;
            acc[10] += py * tx; acc[11] += py * ty; acc[12] += py * tz;
            acc[13] += pz * tx; acc[14] += pz * ty; acc[15] += pz * tz;
        }
    }

#pragma unroll
    for (int i = 0; i < 16; ++i) acc[i] = wave_sum(acc[i]);

    __shared__ float red[NW][16];
    __shared__ float Ssum[16];
    __shared__ float C[13];
    const int wave = tid >> 6, lane = tid & 63;
    if (lane == 0) {
#pragma unroll
        for (int i = 0; i < 16; ++i) red[wave][i] = acc[i];
    }
    __syncthreads();
    if (tid < 16) {
        float s = 0.f;
#pragma unroll
        for (int w = 0; w < NW; ++w) s += red[w][tid];
        Ssum[tid] = s;
    }
    __syncthreads();

    if (tid == 0) {
        const float cnt = Ssum[0];
        const float inv = 1.f / cnt;
        const float cpx = Ssum[1]*inv, cpy = Ssum[2]*inv, cpz = Ssum[3]*inv;
        const float ctx = Ssum[4]*inv, cty = Ssum[5]*inv, ctz = Ssum[6]*inv;
        const float Sxx = Ssum[7]  - cnt*cpx*ctx;
        const float Sxy = Ssum[8]  - cnt*cpx*cty;
        const float Sxz = Ssum[9]  - cnt*cpx*ctz;
        const float Syx = Ssum[10] - cnt*cpy*ctx;
        const float Syy = Ssum[11] - cnt*cpy*cty;
        const float Syz = Ssum[12] - cnt*cpy*ctz;
        const float Szx = Ssum[13] - cnt*cpz*ctx;
        const float Szy = Ssum[14] - cnt*cpz*cty;
        const float Szz = Ssum[15] - cnt*cpz*ctz;
        // Horn's 4x4 N: max-eigvec quaternion == Kabsch R with det(+1) fix.
        float N00 =  Sxx + Syy + Szz;
        float N01 =  Syz - Szy;
        float N02 =  Szx - Sxz;
        float N03 =  Sxy - Syx;
        float N11 =  Sxx - Syy - Szz;
        float N12 =  Sxy + Syx;
        float N13 =  Szx + Sxz;
        float N22 = -Sxx + Syy - Szz;
        float N23 =  Syz + Szy;
        float N33 = -Sxx - Syy + Szz;
        const float fro = sqrtf(N00*N00 + N11*N11 + N22*N22 + N33*N33 +
              2.f*(N01*N01 + N02*N02 + N03*N03 + N12*N12 + N13*N13 + N23*N23));
        // Spectral radius of (N/fro + I) <= 2; norm every 8 iters (R5 fix).
        const float isc = 1.f / (fro + 1e-30f);
        N00*=isc; N01*=isc; N02*=isc; N03*=isc; N11*=isc;
        N12*=isc; N13*=isc; N22*=isc; N23*=isc; N33*=isc;

        float qw = 1.f, qx = 0.1f, qy = 0.2f, qz = 0.3f;
        for (int it = 0; it < 96; ++it) {
            float nw = N00*qw + N01*qx + N02*qy + N03*qz + qw;
            float nx = N01*qw + N11*qx + N12*qy + N13*qz + qx;
            float ny = N02*qw + N12*qx + N22*qy + N23*qz + qy;
            float nz = N03*qw + N13*qx + N23*qy + N33*qz + qz;
            if ((it & 7) == 7) {
                const float r = rsqrtf(nw*nw + nx*nx + ny*ny + nz*nz);
                nw *= r; nx *= r; ny *= r; nz *= r;
            }
            qw = nw; qx = nx; qy = ny; qz = nz;
        }
        const float r = rsqrtf(qw*qw + qx*qx + qy*qy + qz*qz);
        qw *= r; qx *= r; qy *= r; qz *= r;
        const float R00 = 1.f - 2.f*(qy*qy + qz*qz);
        const float R01 = 2.f*(qx*qy - qw*qz);
        const float R02 = 2.f*(qx*qz + qw*qy);
        const float R10 = 2.f*(qx*qy + qw*qz);
        const float R11 = 1.f - 2.f*(qx*qx + qz*qz);
        const float R12 = 2.f*(qy*qz - qw*qx);
        const float R20 = 2.f*(qx*qz - qw*qy);
        const float R21 = 2.f*(qy*qz + qw*qx);
        const float R22 = 1.f - 2.f*(qx*qx + qy*qy);
        C[0]=R00; C[1]=R01; C[2]=R02;
        C[3]=R10; C[4]=R11; C[5]=R12;
        C[6]=R20; C[7]=R21; C[8]=R22;
        C[9]  = ctx - (R00*cpx + R01*cpy + R02*cpz);
        C[10] = cty - (R10*cpx + R11*cpy + R12*cpz);
        C[11] = ctz - (R20*cpx + R21*cpy + R22*cpz);
        C[12] = cnt;
    }
    __syncthreads();

    // ---- loss: register-resident masked P, tgt re-read (L3-warm) ----
    const float C0=C[0], C1=C[1], C2=C[2], C3=C[3], C4=C[4],  C5=C[5];
    const float C6=C[6], C7=C[7], C8=C[8], C9=C[9], C10=C[10], C11=C[11];
    float ls = 0.f;
#pragma unroll
    for (int g = 0; g < PPT / 4; ++g) {
        const float4 tA = t4[3*g], tB = t4[3*g+1], tC = t4[3*g+2];
        const float T[4][3] = {{tA.x,tA.y,tA.z},{tA.w,tB.x,tB.y},
                               {tB.z,tB.w,tC.x},{tC.y,tC.z,tC.w}};
#pragma unroll
        for (int k = 0; k < 4; ++k) {
            const int idx = g * 4 + k;
            const float mk = (float)((mbits >> idx) & 1u);
            const float ax = C0*Px[idx] + C1*Py[idx] + C2*Pz[idx] + C9;
            const float ay = C3*Px[idx] + C4*Py[idx] + C5*Pz[idx] + C10;
            const float az = C6*Px[idx] + C7*Py[idx] + C8*Pz[idx] + C11;
            ls += mk * (huber(ax - T[k][0]) + huber(ay - T[k][1]) +
                        huber(az - T[k][2]));
        }
    }
    ls = wave_sum(ls);
    __shared__ float redl[NW];
    if (lane == 0) redl[wave] = ls;
    __syncthreads();
    if (tid == 0) {
        float t = 0.f;
#pragma unroll
        for (int w = 0; w < NW; ++w) t += redl[w];
        bl[b] = t;
        bc[b] = C[12];
    }
}

// ---- final scalar = sum(bl) / sum(bc) over 256 batches ----
__global__ __launch_bounds__(NB) void final_kernel(
    const float* __restrict__ bl, const float* __restrict__ bc,
    float* __restrict__ out)
{
    const int tid = threadIdx.x;
    float ls = bl[tid];
    float cs = bc[tid];
    ls = wave_sum(ls);
    cs = wave_sum(cs);
    __shared__ float rl[4], rc[4];
    const int wave = tid >> 6, lane = tid & 63;
    if (lane == 0) { rl[wave] = ls; rc[wave] = cs; }
    __syncthreads();
    if (tid == 0)
        out[0] = (rl[0]+rl[1]+rl[2]+rl[3]) / (rc[0]+rc[1]+rc[2]+rc[3]);
}

extern "C" void kernel_launch(void* const* d_in, const int* in_sizes, int n_in,
                              void* d_out, int out_size, void* d_ws, size_t ws_size,
                              hipStream_t stream) {
    const float* pred = (const float*)d_in[0];
    const float* tgt  = (const float*)d_in[1];
    const int*   mask = (const int*)d_in[2];
    float* out = (float*)d_out;

    // ws layout (floats): bl[256] | bc[256]
    float* bl = (float*)d_ws;
    float* bc = bl + NB;

    fused_kernel<<<NB, TPB, 0, stream>>>(pred, tgt, mask, bl, bc);
    final_kernel<<<1, NB, 0, stream>>>(bl, bc, out);
}